// Round 3
// baseline (1341.754 us; speedup 1.0000x reference)
//
#include <hip/hip_runtime.h>

// GNNLayer fused kernel — fp32 baseline (round 3: resubmit of round-2 kernel;
// both prior rounds died on infra before the kernel ever ran).
// B=16, N=10000, D=128. One block = 64 tour-consecutive nodes of one batch.
// Algebraic reduction: 6*D^2 MACs/node (shared x@W1a, shared c=x@W1b used as
// both prev/next contribution, summed layer-2 input) vs 12*D^2 naive.
//
// Hardening: (a) tour dtype sniffed in-kernel (int32 vs int64 — JAX
// x64-disabled makes astype(int64) an int32 buffer; harness doc says
// "integer -> const int*"); (b) all gather/scatter indices clamped to [0,N)
// so a wrong assumption yields a wrong answer, not a dead container.

#define BB 16
#define NN 10000
#define DD 128
#define TT 64
#define NTHREADS 256
#define CHUNK 16
#define EPS_LN 1e-5f

struct Smem {
    float XT[128][68];   // x^T: cols 0..63 = tile nodes, 64 = prev-halo, 65 = next-halo
    float B2[128][68];   // reused transposed buffer: c^T -> s^T -> msg^T -> z^T
    float WB[CHUNK][128]; // weight chunk (16 k-rows x 128 out-dims)
};

__device__ __forceinline__ float silu_f(float x) {
    return x / (1.0f + __expf(-x));
}

// tour[i] with dtype resolved at runtime; clamped to [0, NN).
__device__ __forceinline__ int tour_at(const int* tw, bool is64, long long i) {
    int v = is64 ? (int)(((const long long*)tw)[i]) : tw[i];
    return (v < 0 || v >= NN) ? 0 : v;
}

// acc[i][j] += sum_k IN[k][node] * W0[k*128 + d] over k=0..127 for the 64-node
// main tile; if HALO, also acch += sum_k IN[k][64+hrow] * W0[k*128+hd].
template<bool HALO>
__device__ __forceinline__ void gemm_tile(Smem& sm, const float (&IN)[128][68],
                                          const float* __restrict__ W0,
                                          float (&acc)[4][8], float& acch)
{
    const int tid = threadIdx.x;
    const int dg = tid & 15;        // dim group: 16 groups x 8 dims
    const int ng = tid >> 4;        // node group: 16 groups x 4 nodes
    const int wk = tid >> 4;        // weight-load row within chunk
    const int wd = (tid & 15) * 8;  // weight-load dim start
    const int hrow = tid >> 7;      // halo row 0/1
    const int hd = tid & 127;       // halo dim
    float4 w0 = *(const float4*)(W0 + wk * 128 + wd);
    float4 w1 = *(const float4*)(W0 + wk * 128 + wd + 4);
    for (int k0 = 0; k0 < 128; k0 += CHUNK) {
        __syncthreads();                       // prior chunk fully consumed
        *(float4*)&sm.WB[wk][wd]     = w0;
        *(float4*)&sm.WB[wk][wd + 4] = w1;
        __syncthreads();
        if (k0 + CHUNK < 128) {                // prefetch next chunk (hides HBM/L2 latency)
            w0 = *(const float4*)(W0 + (k0 + CHUNK + wk) * 128 + wd);
            w1 = *(const float4*)(W0 + (k0 + CHUNK + wk) * 128 + wd + 4);
        }
        #pragma unroll
        for (int kk = 0; kk < CHUNK; ++kk) {
            const float4 xv = *(const float4*)&IN[k0 + kk][ng * 4];
            const float4 wa = *(const float4*)&sm.WB[kk][dg * 8];
            const float4 wb = *(const float4*)&sm.WB[kk][dg * 8 + 4];
            const float xs[4] = {xv.x, xv.y, xv.z, xv.w};
            const float ws[8] = {wa.x, wa.y, wa.z, wa.w, wb.x, wb.y, wb.z, wb.w};
            #pragma unroll
            for (int i = 0; i < 4; ++i)
                #pragma unroll
                for (int j = 0; j < 8; ++j)
                    acc[i][j] = fmaf(xs[i], ws[j], acc[i][j]);
            if (HALO)
                acch = fmaf(IN[k0 + kk][64 + hrow], sm.WB[kk][hd], acch);
        }
    }
}

__global__ __launch_bounds__(NTHREADS, 2)
void gnn_layer_kernel(const float* __restrict__ h, const int* __restrict__ tour_raw,
                      const float* __restrict__ W1m, const float* __restrict__ b1m,
                      const float* __restrict__ W2m, const float* __restrict__ b2m,
                      const float* __restrict__ W1u, const float* __restrict__ b1u,
                      const float* __restrict__ W2u, const float* __restrict__ b2u,
                      const float* __restrict__ gma, const float* __restrict__ bta,
                      float* __restrict__ out)
{
    __shared__ Smem sm;
    const int tid = threadIdx.x;
    const int b   = blockIdx.y;
    const int t0  = blockIdx.x * TT;
    const int Tl  = min(TT, NN - t0);   // tail tile = 16 nodes

    // ---- tour dtype sniff: int64 high-words at int32-positions 1,3 are both 0;
    // an int32 permutation can have at most one 0 among two distinct entries.
    const bool is64 = (tour_raw[1] == 0) && (tour_raw[3] == 0);
    const long long tbase = (long long)b * NN;
    const float* hb = h + (long long)b * NN * DD;

    const int dg = tid & 15;
    const int ng = tid >> 4;

    // ---------- gather: XT[d][col] = h[b, tour[t0+col], d] (transposed) ----------
    for (int idx = tid; idx < 66 * 32; idx += NTHREADS) {
        const int col = idx >> 5;
        const int d0  = (idx & 31) * 4;
        int gi = 0; bool valid = true;
        if (col < 64) {
            if (col < Tl) gi = t0 + col; else valid = false;   // pad cols -> 0
        } else if (col == 64) {
            gi = (t0 == 0) ? (NN - 1) : (t0 - 1);              // prev halo (wrap)
        } else {
            gi = (t0 + Tl == NN) ? 0 : (t0 + Tl);              // next halo (wrap)
        }
        float4 v = make_float4(0.f, 0.f, 0.f, 0.f);
        if (valid) {
            const int node = tour_at(tour_raw, is64, tbase + gi);
            v = *(const float4*)(hb + (long long)node * DD + d0);
        }
        sm.XT[d0 + 0][col] = v.x;
        sm.XT[d0 + 1][col] = v.y;
        sm.XT[d0 + 2][col] = v.z;
        sm.XT[d0 + 3][col] = v.w;
    }
    __syncthreads();

    float dummy = 0.f;

    // ---------- stage 1: c = x @ W1b  (W1m rows 128..255), incl. 2 halo rows ----------
    float accc[4][8] = {};
    float acch = 0.f;
    gemm_tile<true>(sm, sm.XT, W1m + 128 * 128, accc, acch);
    __syncthreads();
    #pragma unroll
    for (int i = 0; i < 4; ++i)
        #pragma unroll
        for (int j = 0; j < 8; ++j)
            sm.B2[dg * 8 + j][ng * 4 + i] = accc[i][j];
    sm.B2[tid & 127][64 + (tid >> 7)] = acch;   // halo c
    __syncthreads();

    // ---------- stage 2: a = x @ W1a  (W1m rows 0..127) ----------
    float acca[4][8] = {};
    gemm_tile<false>(sm, sm.XT, W1m, acca, dummy);

    // ---------- stage 3: s = silu(a + c_prev + b1m) + silu(a + c_next + b1m) ----------
    const float4 bm0 = *(const float4*)(b1m + dg * 8);
    const float4 bm1 = *(const float4*)(b1m + dg * 8 + 4);
    const float bm[8] = {bm0.x, bm0.y, bm0.z, bm0.w, bm1.x, bm1.y, bm1.z, bm1.w};
    float sbuf[4][8];
    #pragma unroll
    for (int i = 0; i < 4; ++i) {
        const int n  = ng * 4 + i;
        const int jp = (n == 0)      ? 64 : n - 1;
        const int jn = (n == Tl - 1) ? 65 : n + 1;
        #pragma unroll
        for (int j = 0; j < 8; ++j) {
            const float aij = acca[i][j] + bm[j];
            const float cp  = sm.B2[dg * 8 + j][jp];
            const float cn  = sm.B2[dg * 8 + j][jn];
            sbuf[i][j] = silu_f(aij + cp) + silu_f(aij + cn);
        }
    }
    __syncthreads();   // everyone done reading c^T
    #pragma unroll
    for (int i = 0; i < 4; ++i)
        #pragma unroll
        for (int j = 0; j < 8; ++j)
            sm.B2[dg * 8 + j][ng * 4 + i] = sbuf[i][j];   // B2 = s^T
    __syncthreads();

    // ---------- stage 4: msg = s @ W2m + 2*b2m ----------
    float accm[4][8] = {};
    gemm_tile<false>(sm, sm.B2, W2m, accm, dummy);
    {
        const float4 c0 = *(const float4*)(b2m + dg * 8);
        const float4 c1 = *(const float4*)(b2m + dg * 8 + 4);
        const float bb2[8] = {c0.x, c0.y, c0.z, c0.w, c1.x, c1.y, c1.z, c1.w};
        #pragma unroll
        for (int i = 0; i < 4; ++i)
            #pragma unroll
            for (int j = 0; j < 8; ++j)
                accm[i][j] += 2.0f * bb2[j];
    }
    __syncthreads();
    #pragma unroll
    for (int i = 0; i < 4; ++i)
        #pragma unroll
        for (int j = 0; j < 8; ++j)
            sm.B2[dg * 8 + j][ng * 4 + i] = accm[i][j];   // B2 = msg^T
    __syncthreads();

    // ---------- stage 5: z = silu(x @ W1u[:128] + msg @ W1u[128:] + b1u) ----------
    float accu[4][8] = {};
    gemm_tile<false>(sm, sm.XT, W1u, accu, dummy);
    gemm_tile<false>(sm, sm.B2, W1u + 128 * 128, accu, dummy);
    {
        const float4 c0 = *(const float4*)(b1u + dg * 8);
        const float4 c1 = *(const float4*)(b1u + dg * 8 + 4);
        const float bu[8] = {c0.x, c0.y, c0.z, c0.w, c1.x, c1.y, c1.z, c1.w};
        #pragma unroll
        for (int i = 0; i < 4; ++i)
            #pragma unroll
            for (int j = 0; j < 8; ++j)
                accu[i][j] = silu_f(accu[i][j] + bu[j]);
    }
    __syncthreads();
    #pragma unroll
    for (int i = 0; i < 4; ++i)
        #pragma unroll
        for (int j = 0; j < 8; ++j)
            sm.B2[dg * 8 + j][ng * 4 + i] = accu[i][j];   // B2 = z^T
    __syncthreads();

    // ---------- stage 6: v = z @ W2u + b2u; r = x + v; LayerNorm; scatter ----------
    float accv[4][8] = {};
    gemm_tile<false>(sm, sm.B2, W2u, accv, dummy);

    const float4 v0 = *(const float4*)(b2u + dg * 8);
    const float4 v1 = *(const float4*)(b2u + dg * 8 + 4);
    const float bu2[8] = {v0.x, v0.y, v0.z, v0.w, v1.x, v1.y, v1.z, v1.w};
    const float4 g0 = *(const float4*)(gma + dg * 8);
    const float4 g1 = *(const float4*)(gma + dg * 8 + 4);
    const float gg[8] = {g0.x, g0.y, g0.z, g0.w, g1.x, g1.y, g1.z, g1.w};
    const float4 e0 = *(const float4*)(bta + dg * 8);
    const float4 e1 = *(const float4*)(bta + dg * 8 + 4);
    const float ee[8] = {e0.x, e0.y, e0.z, e0.w, e1.x, e1.y, e1.z, e1.w};

    #pragma unroll
    for (int i = 0; i < 4; ++i) {
        const int n = ng * 4 + i;
        float r[8];
        float s1 = 0.f, s2 = 0.f;
        #pragma unroll
        for (int j = 0; j < 8; ++j) {
            const float x = sm.XT[dg * 8 + j][n];
            r[j] = x + accv[i][j] + bu2[j];
            s1 += r[j];
            s2 += r[j] * r[j];
        }
        // reduce across the 16 dim-groups (lanes differing in low 4 bits)
        #pragma unroll
        for (int m = 1; m <= 8; m <<= 1) {
            s1 += __shfl_xor(s1, m, 64);
            s2 += __shfl_xor(s2, m, 64);
        }
        const float mu  = s1 * (1.0f / 128.0f);
        const float var = s2 * (1.0f / 128.0f) - mu * mu;
        const float rs  = rsqrtf(var + EPS_LN);
        if (n < Tl) {
            const int node = tour_at(tour_raw, is64, tbase + t0 + n);
            float* op = out + ((long long)b * NN + node) * DD + dg * 8;
            float4 o0, o1;
            o0.x = (r[0] - mu) * rs * gg[0] + ee[0];
            o0.y = (r[1] - mu) * rs * gg[1] + ee[1];
            o0.z = (r[2] - mu) * rs * gg[2] + ee[2];
            o0.w = (r[3] - mu) * rs * gg[3] + ee[3];
            o1.x = (r[4] - mu) * rs * gg[4] + ee[4];
            o1.y = (r[5] - mu) * rs * gg[5] + ee[5];
            o1.z = (r[6] - mu) * rs * gg[6] + ee[6];
            o1.w = (r[7] - mu) * rs * gg[7] + ee[7];
            *(float4*)op       = o0;
            *(float4*)(op + 4) = o1;
        }
    }
}

extern "C" void kernel_launch(void* const* d_in, const int* in_sizes, int n_in,
                              void* d_out, int out_size, void* d_ws, size_t ws_size,
                              hipStream_t stream)
{
    const float* h    = (const float*)d_in[0];
    const int*   tour = (const int*)d_in[1];   // dtype (i32 vs i64) sniffed in-kernel
    const float* W1m  = (const float*)d_in[2];
    const float* b1m  = (const float*)d_in[3];
    const float* W2m  = (const float*)d_in[4];
    const float* b2m  = (const float*)d_in[5];
    const float* W1u  = (const float*)d_in[6];
    const float* b1u  = (const float*)d_in[7];
    const float* W2u  = (const float*)d_in[8];
    const float* b2u  = (const float*)d_in[9];
    const float* gma  = (const float*)d_in[10];
    const float* bta  = (const float*)d_in[11];
    float*       out  = (float*)d_out;

    dim3 grid((NN + TT - 1) / TT, BB);
    dim3 block(NTHREADS);
    gnn_layer_kernel<<<grid, block, 0, stream>>>(h, tour, W1m, b1m, W2m, b2m,
                                                 W1u, b1u, W2u, b2u, gma, bta, out);
}

// Round 5
// 256.041 us; speedup vs baseline: 5.2404x; 5.2404x over previous
//
#include <hip/hip_runtime.h>

// GNNLayer fused kernel — round 5: resubmit of round-4 bf16 MFMA rewrite
// (round 4 died on GPU acquisition; kernel never ran; full re-audit clean).
// Prior measured (fp32 VALU, round 3): 1307us, SQ_LDS_BANK_CONFLICT=4.97e8
// (~62% of cycles), VALUBusy 20%, MfmaUtil 0. Fix: MFMA GEMM stages +
// XOR-swizzled LDS ((granule^(row&7))<<4 -> 2-way conflicts = free, m136).
// Structure: 62 main nodes + 2 halo rows = 64 rows/block; halo c computed by
// the same MFMA pass. 6 phases (one per weight image), weights pre-packed to
// d_ws (bf16 W^T, swizzle baked in) by pack_weights.

#define BB 16
#define NN 10000
#define DD 128
#define TT 62
#define NTHREADS 256
#define EPS_LN 1e-5f

typedef __attribute__((ext_vector_type(8))) short short8v;           // 8 bf16 (4 VGPR)
typedef __attribute__((ext_vector_type(8))) unsigned short ushort8v;
typedef __attribute__((ext_vector_type(4))) float f32x4;

__device__ __forceinline__ unsigned short bf16_rne(float f) {
    union { float f; unsigned u; } v; v.f = f;
    unsigned r = v.u + 0x7FFFu + ((v.u >> 16) & 1u);
    return (unsigned short)(r >> 16);
}
__device__ __forceinline__ float bf16f(unsigned short h) {
    union { unsigned u; float f; } v; v.u = ((unsigned)h) << 16;
    return v.f;
}
__device__ __forceinline__ float silu_f(float x) { return x / (1.0f + __expf(-x)); }

// tour[i], dtype (i32 vs i64) resolved at runtime, clamped to [0,NN)
__device__ __forceinline__ int tour_at(const int* tw, bool is64, long long i) {
    int v = is64 ? (int)(((const long long*)tw)[i]) : tw[i];
    return (v < 0 || v >= NN) ? 0 : v;
}

// byte offset of bf16 element k within a 256B row, XOR-swizzled on 16B granules
__device__ __forceinline__ int swz(int row, int k) {
    return (((k >> 3) ^ (row & 7)) << 4) | ((k & 7) << 1);
}

// ---------------- weight pack kernel ----------------
// images (each [n=0..127][k=0..127] bf16, 32KB, swizzle baked):
// 0:W1b=W1m[128+k][n] 1:W1a=W1m[k][n] 2:W2m 3:W1u_x=W1u[k][n] 4:W1u_m=W1u[128+k][n] 5:W2u
__global__ void pack_weights(const float* __restrict__ W1m, const float* __restrict__ W2m,
                             const float* __restrict__ W1u, const float* __restrict__ W2u,
                             unsigned short* __restrict__ wp)
{
    int t = blockIdx.x * blockDim.x + threadIdx.x;   // 12288 granule tasks
    if (t >= 6 * 128 * 16) return;
    int img = t >> 11;       // /2048
    int r   = t & 2047;
    int n   = r >> 4;
    int g   = r & 15;
    const float* src; int koff;
    switch (img) {
      case 0: src = W1m; koff = 128; break;
      case 1: src = W1m; koff = 0;   break;
      case 2: src = W2m; koff = 0;   break;
      case 3: src = W1u; koff = 0;   break;
      case 4: src = W1u; koff = 128; break;
      default: src = W2u; koff = 0;  break;
    }
    ushort8v v;
    #pragma unroll
    for (int j = 0; j < 8; ++j) {
        int k = g * 8 + j;
        v[j] = bf16_rne(src[(koff + k) * 128 + n]);
    }
    *(ushort8v*)((char*)wp + img * 32768 + n * 256 + ((g ^ (n & 7)) << 4)) = v;
}

// ---------------- main kernel ----------------
__global__ __launch_bounds__(NTHREADS, 2)
void gnn_mfma_kernel(const float* __restrict__ h, const int* __restrict__ tour_raw,
                     const unsigned short* __restrict__ wp,
                     const float* __restrict__ b1m, const float* __restrict__ b2m,
                     const float* __restrict__ b1u, const float* __restrict__ b2u,
                     const float* __restrict__ gma, const float* __restrict__ bta,
                     float* __restrict__ out)
{
    __shared__ unsigned char lds[81920];        // 80KB exact -> 2 blocks/CU
    unsigned char* XA = lds;                    // x  bf16 [64][128] swizzled
    unsigned char* CB = lds + 16384;            // c  bf16
    unsigned char* SB = lds + 32768;            // s/msg/z bf16 (reused)
    unsigned char* WS = lds + 49152;            // weight image slot (32KB)

    const int tid  = threadIdx.x;
    const int b    = blockIdx.y;
    const int t0   = blockIdx.x * TT;
    const int Tl   = min(TT, NN - t0);
    const int lane = tid & 63;
    const int w    = tid >> 6;
    const int dl   = lane & 15;

    const bool is64 = (tour_raw[1] == 0) && (tour_raw[3] == 0);
    const long long tbase = (long long)b * NN;
    const float* hb = h + (long long)b * NN * DD;

    // per-lane small vectors: dim(nt) = nt*16 + dl
    float vb1m[8], vb2m[8], vb1u[8], vb2u[8], vg[8], vbt[8];
    #pragma unroll
    for (int nt = 0; nt < 8; ++nt) {
        int d = nt * 16 + dl;
        vb1m[nt] = b1m[d]; vb2m[nt] = b2m[d];
        vb1u[nt] = b1u[d]; vb2u[nt] = b2u[d];
        vg[nt]   = gma[d]; vbt[nt]  = bta[d];
    }

    // ---- gather x -> XA (bf16, swizzled). rows 0..61 main, 62 prev-halo, 63 next-halo
    #pragma unroll
    for (int p = 0; p < 4; ++p) {
        int id  = tid + p * NTHREADS;   // 0..1023 (64 rows x 16 granules)
        int row = id >> 4;
        int gg  = id & 15;
        int gi;
        if (row < TT)       gi = (row < Tl) ? (t0 + row) : t0;            // main / junk
        else if (row == TT) gi = (t0 == 0) ? (NN - 1) : (t0 - 1);         // prev halo
        else                gi = (t0 + Tl >= NN) ? 0 : (t0 + Tl);         // next halo
        int node = tour_at(tour_raw, is64, tbase + gi);
        const float4 f0 = *(const float4*)(hb + node * DD + gg * 8);
        const float4 f1 = *(const float4*)(hb + node * DD + gg * 8 + 4);
        ushort8v vv;
        vv[0] = bf16_rne(f0.x); vv[1] = bf16_rne(f0.y); vv[2] = bf16_rne(f0.z); vv[3] = bf16_rne(f0.w);
        vv[4] = bf16_rne(f1.x); vv[5] = bf16_rne(f1.y); vv[6] = bf16_rne(f1.z); vv[7] = bf16_rne(f1.w);
        *(ushort8v*)(XA + row * 256 + ((gg ^ (row & 7)) << 4)) = vv;
    }

    f32x4 acc[8], acc_a[8], acc_z[8];
    short8v afr[4];
    ushort8v wreg[8];

    auto wload = [&](int img) {
        #pragma unroll
        for (int r = 0; r < 8; ++r)
            wreg[r] = *(const ushort8v*)((const char*)wp + img * 32768 + r * 4096 + tid * 16);
    };
    auto wstore = [&]() {
        #pragma unroll
        for (int r = 0; r < 8; ++r)
            *(ushort8v*)(WS + r * 4096 + tid * 16) = wreg[r];
    };
    auto load_afrag = [&](const unsigned char* P) {
        int row = w * 16 + (lane & 15);
        #pragma unroll
        for (int ks = 0; ks < 4; ++ks) {
            int g = ks * 4 + (lane >> 4);
            afr[ks] = *(const short8v*)(P + row * 256 + ((g ^ (row & 7)) << 4));
        }
    };
    auto zero8 = [&](f32x4* A) {
        #pragma unroll
        for (int nt = 0; nt < 8; ++nt) A[nt] = (f32x4){0.f, 0.f, 0.f, 0.f};
    };
    auto gemm_acc = [&](f32x4* A) {
        #pragma unroll
        for (int ks = 0; ks < 4; ++ks) {
            #pragma unroll
            for (int nt = 0; nt < 8; ++nt) {
                int n = nt * 16 + dl;
                int g = ks * 4 + (lane >> 4);
                short8v bf = *(const short8v*)(WS + n * 256 + ((g ^ (n & 7)) << 4));
                A[nt] = __builtin_amdgcn_mfma_f32_16x16x32_bf16(afr[ks], bf, A[nt], 0, 0, 0);
            }
        }
    };
    auto store_cd = [&](unsigned char* P, f32x4* A) {    // C layout: row=(l>>4)*4+reg, col=l&15 (m89)
        #pragma unroll
        for (int nt = 0; nt < 8; ++nt) {
            int d = nt * 16 + dl;
            #pragma unroll
            for (int reg = 0; reg < 4; ++reg) {
                int row = w * 16 + (lane >> 4) * 4 + reg;
                *(unsigned short*)(P + row * 256 + swz(row, d)) = bf16_rne(A[nt][reg]);
            }
        }
    };

    // ================= phase pipeline =================
    wload(0);

    // phase 0: c = x @ W1b   (incl. halo rows 62,63 via normal MFMA path)
    __syncthreads();                 // gather visible
    wstore(); wload(1);
    load_afrag(XA);
    zero8(acc);
    __syncthreads();
    gemm_acc(acc);
    store_cd(CB, acc);

    // phase 1: a = x @ W1a ; epilogue s = silu(a+c_prev+b1m)+silu(a+c_next+b1m)
    __syncthreads();
    wstore(); wload(2);
    // afr still holds x fragments from phase 0 — reuse
    zero8(acc_a);
    __syncthreads();
    gemm_acc(acc_a);
    #pragma unroll
    for (int nt = 0; nt < 8; ++nt) {
        int d = nt * 16 + dl;
        #pragma unroll
        for (int reg = 0; reg < 4; ++reg) {
            int row = w * 16 + (lane >> 4) * 4 + reg;
            int jp = (row == 0) ? 62 : row - 1;
            int jn = (row >= Tl - 1) ? 63 : row + 1;
            float aij = acc_a[nt][reg] + vb1m[nt];
            float cp = bf16f(*(const unsigned short*)(CB + jp * 256 + swz(jp, d)));
            float cn = bf16f(*(const unsigned short*)(CB + jn * 256 + swz(jn, d)));
            acc_a[nt][reg] = silu_f(aij + cp) + silu_f(aij + cn);
        }
    }
    store_cd(SB, acc_a);             // SB = s

    // phase 2: msg = s @ W2m + 2*b2m
    __syncthreads();
    wstore(); wload(3);
    load_afrag(SB);
    zero8(acc);
    __syncthreads();
    gemm_acc(acc);
    #pragma unroll
    for (int nt = 0; nt < 8; ++nt) {
        #pragma unroll
        for (int reg = 0; reg < 4; ++reg) acc[nt][reg] += 2.0f * vb2m[nt];
    }
    store_cd(SB, acc);               // SB = msg (in-place: s frags already in regs)

    // phase 3: z_partial = x @ W1u_x
    __syncthreads();
    wstore(); wload(4);
    load_afrag(XA);
    zero8(acc_z);
    __syncthreads();
    gemm_acc(acc_z);

    // phase 4: z += msg @ W1u_m ; epilogue z = silu(z + b1u)
    __syncthreads();
    wstore(); wload(5);
    load_afrag(SB);
    __syncthreads();
    gemm_acc(acc_z);
    #pragma unroll
    for (int nt = 0; nt < 8; ++nt) {
        #pragma unroll
        for (int reg = 0; reg < 4; ++reg)
            acc_z[nt][reg] = silu_f(acc_z[nt][reg] + vb1u[nt]);
    }
    store_cd(SB, acc_z);             // SB = z

    // phase 5: v = z @ W2u ; epilogue LN(x + v + b2u) -> scatter
    __syncthreads();
    wstore();
    load_afrag(SB);
    zero8(acc);
    __syncthreads();
    gemm_acc(acc);

    #pragma unroll
    for (int reg = 0; reg < 4; ++reg) {
        int row = w * 16 + (lane >> 4) * 4 + reg;
        bool valid = row < Tl;
        int node = tour_at(tour_raw, is64, tbase + t0 + (valid ? row : 0));
        float r8[8]; float s1 = 0.f, s2 = 0.f;
        #pragma unroll
        for (int nt = 0; nt < 8; ++nt) {
            int d = nt * 16 + dl;
            float xg = hb[node * DD + d];            // fp32 residual (L3-hot re-read)
            float rv = xg + acc[nt][reg] + vb2u[nt];
            r8[nt] = rv; s1 += rv; s2 += rv * rv;
        }
        #pragma unroll
        for (int m = 1; m <= 8; m <<= 1) {
            s1 += __shfl_xor(s1, m, 64);
            s2 += __shfl_xor(s2, m, 64);
        }
        float mu  = s1 * (1.0f / 128.0f);
        float var = s2 * (1.0f / 128.0f) - mu * mu;
        float rs  = rsqrtf(var + EPS_LN);
        if (valid) {
            float* op = out + ((long long)b * NN + node) * DD;
            #pragma unroll
            for (int nt = 0; nt < 8; ++nt) {
                int d = nt * 16 + dl;
                op[d] = (r8[nt] - mu) * rs * vg[nt] + vbt[nt];
            }
        }
    }
}

extern "C" void kernel_launch(void* const* d_in, const int* in_sizes, int n_in,
                              void* d_out, int out_size, void* d_ws, size_t ws_size,
                              hipStream_t stream)
{
    const float* h    = (const float*)d_in[0];
    const int*   tour = (const int*)d_in[1];
    const float* W1m  = (const float*)d_in[2];
    const float* b1m  = (const float*)d_in[3];
    const float* W2m  = (const float*)d_in[4];
    const float* b2m  = (const float*)d_in[5];
    const float* W1u  = (const float*)d_in[6];
    const float* b1u  = (const float*)d_in[7];
    const float* W2u  = (const float*)d_in[8];
    const float* b2u  = (const float*)d_in[9];
    const float* gma  = (const float*)d_in[10];
    const float* bta  = (const float*)d_in[11];
    float*       out  = (float*)d_out;
    unsigned short* wp = (unsigned short*)d_ws;     // 6*32KB = 192KB packed weights

    pack_weights<<<48, NTHREADS, 0, stream>>>(W1m, W2m, W1u, W2u, wp);

    dim3 grid((NN + TT - 1) / TT, BB);
    gnn_mfma_kernel<<<grid, NTHREADS, 0, stream>>>(h, tour, wp, b1m, b2m, b1u, b2u,
                                                   gma, bta, out);
}